// Round 11
// baseline (155.870 us; speedup 1.0000x reference)
//
#include <hip/hip_runtime.h>

#define G_ 100
#define T_ 24
#define GP1 101
#define TILE (G_ * T_)        // 2400 floats per (b,pass) tile
#define VPB (TILE / 4)        // 600 float4 per tile
#define WPB 4                 // waves per block: 2 b's x 2 passes
#define BLOCK (64 * WPB)

typedef float vfloat4 __attribute__((ext_vector_type(4)));

// Merit-order chunk: ord ranks via LDS broadcast -> SGPR (readfirstlane),
// batch N scattered 96B-row cap loads from global (one vmcnt window),
// price = praw[g] (slack price > all gen prices => rank 100 is the slack),
// serial clip-scan, allocs into the wave-private LDS tile column.
template<int N>
__device__ __forceinline__ void scan_chunk(int k0, int p,
    const float* __restrict__ capp,          // R_p[b] + t (per-lane)
    const int* __restrict__ s_ord, const float* __restrict__ s_praw,
    float* __restrict__ ldscol,              // tw + t
    float dem, float& before, float& objp)
{
    int gg[N]; float pr[N], cap[N];
#pragma unroll
    for (int j = 0; j < N; ++j)
        gg[j] = __builtin_amdgcn_readfirstlane(s_ord[p * GP1 + k0 + j]);
#pragma unroll
    for (int j = 0; j < N; ++j) cap[j] = capp[gg[j] * T_];   // N loads in flight
#pragma unroll
    for (int j = 0; j < N; ++j)
        pr[j] = __int_as_float(__builtin_amdgcn_readfirstlane(
                    ((const int*)s_praw)[p * GP1 + gg[j]]));  // SGPR price
#pragma unroll
    for (int j = 0; j < N; ++j) {
        float a = fminf(fmaxf(dem - before, 0.f), cap[j]);
        before += cap[j];
        objp = fmaf(pr[j], a, objp);
        ldscol[gg[j] * T_] = a;              // ds_write, own column
    }
}

__global__ __launch_bounds__(BLOCK, 4) void dispatch_kernel(
    const float* __restrict__ R_up, const float* __restrict__ R_dn,
    const float* __restrict__ omega, const float* __restrict__ b_G,
    const float* __restrict__ voll, const float* __restrict__ vosp,
    const float* __restrict__ ru, const float* __restrict__ rd,
    float* __restrict__ out, int B)
{
    __shared__ float s_tile[WPB * TILE];     // 38400 B
    __shared__ float s_praw[2 * GP1];        // raw prices (also the rank->price LUT)
    __shared__ int   s_ord[2 * GP1];
    __shared__ float s_obj[WPB];             // total ~40 KB -> 4 blocks/CU

    const int tid  = threadIdx.x;
    const int w    = tid >> 6;
    const int lane = tid & 63;
    const int b = __builtin_amdgcn_readfirstlane(blockIdx.x * 2 + (w >> 1));
    const int p = __builtin_amdgcn_readfirstlane(w & 1);
    const size_t bgt = (size_t)B * TILE;
    float* __restrict__ tw = &s_tile[w * TILE];   // wave-private tile

    // ---- stage raw prices (sort input) ----
    if (tid < GP1) {
        if (tid < G_) {
            float bg = b_G[tid];
            s_praw[tid]       = ru[0] * bg;  // c_up
            s_praw[GP1 + tid] = rd[0] * bg;  // c_dn
        } else {
            s_praw[tid]       = voll[0];
            s_praw[GP1 + tid] = vosp[0];
        }
    }

    // omega early (hides under sort)
    const int t = (lane < T_) ? lane : 0;
    float om = 0.f;
    if (lane < T_) om = omega[(size_t)b * T_ + t];

    // ---- zero the LDS tile: untouched merit rows must be exactly 0 ----
#pragma unroll
    for (int j = 0; j < 9; ++j) *(vfloat4*)&tw[(lane + j * 64) * 4] = (vfloat4)(0.f);
    if (lane < VPB - 576)       *(vfloat4*)&tw[(lane + 576) * 4]    = (vfloat4)(0.f);
    __syncthreads();

    // ---- per-block stable rank-sort (== jnp.argsort), both passes ----
    if (tid < GP1) {
        float mu = s_praw[tid], md = s_praw[GP1 + tid];
        int r0 = 0, r1 = 0;
        for (int j = 0; j < GP1; ++j) {
            float vu = s_praw[j], vd = s_praw[GP1 + j];
            r0 += (vu < mu) || (vu == mu && j < tid);
            r1 += (vd < md) || (vd == md && j < tid);
        }
        s_ord[r0]       = tid;
        s_ord[GP1 + r1] = tid;
    }
    __syncthreads();

    // ---- merit-order scan: 24 lanes, early-exit, front-loaded chunks ----
    float objp = 0.f;
    if (lane < T_) {
        const float dem = p ? fmaxf(-om, 0.f) : fmaxf(om, 0.f);
        const float* __restrict__ capp = (p ? R_dn : R_up) + (size_t)b * TILE + t;
        float* __restrict__ ldscol = tw + t;

        float before = 0.f;
        scan_chunk<24>( 0, p, capp, s_ord, s_praw, ldscol, dem, before, objp);
        bool run = __any(before < dem);      // one round trip covers most waves
        if (run) { scan_chunk<16>(24, p, capp, s_ord, s_praw, ldscol, dem, before, objp);
                   run = __any(before < dem); }
        if (run) { scan_chunk<16>(40, p, capp, s_ord, s_praw, ldscol, dem, before, objp);
                   run = __any(before < dem); }
        if (run) { scan_chunk< 8>(56, p, capp, s_ord, s_praw, ldscol, dem, before, objp);
                   run = __any(before < dem); }
        if (run) { scan_chunk< 8>(64, p, capp, s_ord, s_praw, ldscol, dem, before, objp);
                   run = __any(before < dem); }
        if (run) { scan_chunk< 8>(72, p, capp, s_ord, s_praw, ldscol, dem, before, objp);
                   run = __any(before < dem); }
        if (run) { scan_chunk< 8>(80, p, capp, s_ord, s_praw, ldscol, dem, before, objp);
                   run = __any(before < dem); }
        if (run) { scan_chunk< 8>(88, p, capp, s_ord, s_praw, ldscol, dem, before, objp);
                   run = __any(before < dem); }
        if (run)   scan_chunk< 4>(96, p, capp, s_ord, s_praw, ldscol, dem, before, objp);

        // slack (rank 100): clip(dem - sum_all, 0, dem); early exit => 0.
        float slackv = fmaxf(dem - before, 0.f);
        objp = fmaf(s_praw[p * GP1 + G_], slackv, objp);   // voll / vosp
        out[2 * bgt + (size_t)p * B * T_ + (size_t)b * T_ + t] = slackv;
    }

    // ---- rt_obj partial: butterfly over the wave (idle lanes hold 0) ----
#pragma unroll
    for (int off = 32; off; off >>= 1) objp += __shfl_xor(objp, off, 64);
    if (lane == 0) s_obj[w] = objp;

    // ---- stream the finished tile out: coalesced plain float4 ----
    __builtin_amdgcn_wave_barrier();         // pin ds_write -> ds_read order
    {
        vfloat4* __restrict__ dst = (vfloat4*)out + ((size_t)p * B + b) * VPB;
#pragma unroll
        for (int j = 0; j < 9; ++j)
            dst[lane + j * 64] = *(const vfloat4*)&tw[(lane + j * 64) * 4];
        if (lane < VPB - 576)
            dst[lane + 576] = *(const vfloat4*)&tw[(lane + 576) * 4];
    }

    // ---- pair up+dn partials per b (barrier hides under stream-out) ----
    __syncthreads();
    if (tid == 0)
        out[2 * bgt + 2 * (size_t)B * T_ + b] = s_obj[0] + s_obj[1];
    if (tid == 128)
        out[2 * bgt + 2 * (size_t)B * T_ + b] = s_obj[2] + s_obj[3];
}

extern "C" void kernel_launch(void* const* d_in, const int* in_sizes, int n_in,
                              void* d_out, int out_size, void* d_ws, size_t ws_size,
                              hipStream_t stream)
{
    const float* R_up  = (const float*)d_in[0];
    const float* R_dn  = (const float*)d_in[1];
    const float* omega = (const float*)d_in[2];
    const float* b_G   = (const float*)d_in[3];
    const float* voll  = (const float*)d_in[4];
    const float* vosp  = (const float*)d_in[5];
    const float* ru    = (const float*)d_in[6];
    const float* rd    = (const float*)d_in[7];

    const int B = in_sizes[0] / TILE;
    float* out = (float*)d_out;

    // single fused kernel: 4 waves/block = 2 b's x 2 passes
    dispatch_kernel<<<B / 2, BLOCK, 0, stream>>>(
        R_up, R_dn, omega, b_G, voll, vosp, ru, rd, out, B);
}